// Round 1
// 333.939 us; speedup vs baseline: 1.0481x; 1.0481x over previous
//
#include <hip/hip_runtime.h>
#include <cmath>

// FFTConv via chunked diagonal SSM + MFMA.
//
// y[n] = tanh( sum_{d>=0} k_d u[n-d] (circular) + D*u[n] ),  k_d = Re sum_p bc_p A_p^d.
// Chunk n = c*128 + r (nc=64 chunks):
//   y[c,r] = sum_j T'[r][j] u[c*128+j]  +  Re sum_p bc_p A_p^{r+1} sB_p[c]
//   T'[r][j] = k_{r-j} (j<=r) + D*(j==r)          (intra-chunk + D skip, one GEMM)
//   sB[c+1]  = A^128 sB[c] + S_in[c],  S_in[c] = sum_j A^{127-j} u[c*128+j]  (GEMM)
// Scan parallelized across 4 waves: each wave warm-starts its 16-chunk range with an
// 8-tap truncated convolution (|A^128|^8 <= 3.4e-5, same bound as the old 8-chunk
// warm-up), then scans serially within its range.
//
// Latency-hiding: all MFMA A-fragments are prefetched one phase early
// (W under u-staging, G under the scan, T' under GEMM2 part 1); barriers pin them.
// LDS tiles are unpadded [64][128] fp16 with a 16-way XOR swizzle (2-way banks, free).

typedef _Float16 half8 __attribute__((ext_vector_type(8)));
typedef _Float16 half4v __attribute__((ext_vector_type(4)));
typedef float floatx16 __attribute__((ext_vector_type(16)));

#define NC 64
#define CM 128
#define A2_BYTES ((size_t)256 * 128 * 256 * 2)
#define W_BYTES  ((size_t)128 * 128 * 2)
#define AM_OFF   (A2_BYTES + W_BYTES)

// XOR-swizzled LDS index (half-element units) for [64][128] fp16 tiles.
// Row stride 256 B; col ^= (row&15)<<3 spreads 16 rows over 16 bank-groups:
// 16B stride-row reads are 2-way (free); preserves 8B/16B alignment (XOR bits 3..6).
#define SWH(r, c) ((((r) << 7)) | ((c) ^ (((r) & 15) << 3)))

__device__ __forceinline__ float fast_tanh(float x) {
    float e2 = __expf(2.0f * x);
    return 1.0f - 2.0f / (e2 + 1.0f);   // exact +/-1 at saturation, no NaN
}

__global__ void fftconv_prep(const float* __restrict__ A_re, const float* __restrict__ A_im,
                             const float* __restrict__ BC_re, const float* __restrict__ BC_im,
                             const float* __restrict__ Dv, char* __restrict__ ws) {
    __shared__ float rr[64], th[64], br[64], bi[64];
    __shared__ float kk[CM];
    const int h = blockIdx.x, tid = threadIdx.x;
    if (tid < 64) {
        float x = A_re[tid], y = A_im[tid];
        rr[tid] = log2f(sqrtf(x * x + y * y));   // log2|A|
        th[tid] = atan2f(y, x);                  // arg(A)
        br[tid] = BC_re[h * 64 + tid];
        bi[tid] = BC_im[h * 64 + tid];
    }
    __syncthreads();
    if (tid < CM) {   // kernel taps k_d, d = 0..127
        float d = (float)tid, s = 0.f;
        for (int p = 0; p < 64; ++p) {
            float mag = exp2f(d * rr[p]);
            float ang = d * th[p];
            s += mag * (br[p] * cosf(ang) - bi[p] * sinf(ang));
        }
        kk[tid] = s;
    }
    __syncthreads();
    _Float16* A2 = (_Float16*)ws + (size_t)h * 128 * 256;
    const float Dh = Dv[h];
    // G part: A2[r][pc] = pc<64 ? Re(bc_p A^{r+1}) : -Im(bc_p A^{r+1})
    for (int idx = tid; idx < 128 * 128; idx += 256) {
        int r = idx >> 7, pc = idx & 127, p = pc & 63;
        float e = (float)(r + 1);
        float mag = exp2f(e * rr[p]);
        float ang = e * th[p];
        float cr = mag * cosf(ang), ci = mag * sinf(ang);
        float val = (pc < 64) ? (br[p] * cr - bi[p] * ci) : -(br[p] * ci + bi[p] * cr);
        A2[r * 256 + pc] = (_Float16)val;
    }
    // T' part: A2[r][128+j] = k_{r-j} (j<=r) + D*(j==r)
    for (int idx = tid; idx < 128 * 128; idx += 256) {
        int r = idx >> 7, j = idx & 127;
        float v = (j <= r) ? kk[r - j] : 0.f;
        if (j == r) v += Dh;
        A2[r * 256 + CM + j] = (_Float16)v;
    }
    if (h == 0) {
        _Float16* W = (_Float16*)(ws + A2_BYTES);   // W[pc][j] = comp(A_p^{127-j})
        for (int idx = tid; idx < 128 * 128; idx += 256) {
            int pc = idx >> 7, j = idx & 127, p = pc & 63;
            float e = (float)(127 - j);
            float mag = exp2f(e * rr[p]);
            float ang = e * th[p];
            float v = (pc < 64) ? mag * cosf(ang) : mag * sinf(ang);
            W[pc * 128 + j] = (_Float16)v;
        }
        if (tid < 64) {   // A^128 fp32 for the scan
            float mag = exp2f(128.f * rr[tid]);
            float ang = 128.f * th[tid];
            float* aM = (float*)(ws + AM_OFF);
            aM[tid] = mag * cosf(ang);
            aM[64 + tid] = mag * sinf(ang);
        }
    }
}

__global__ __launch_bounds__(256, 4)
void fftconv_main(const float* __restrict__ u, const char* __restrict__ ws,
                  float* __restrict__ out) {
    __shared__ __align__(16) _Float16 u16[NC * CM];  // u chunks [c][j], fp16, swizzled
    __shared__ __align__(16) _Float16 S16[NC * CM];  // S_in then sB [c][pc], swizzled

    const int tid = threadIdx.x;
    const int lane = tid & 63;
    const int wv = tid >> 6;
    const int h = blockIdx.x >> 4;
    const int bb = blockIdx.x & 15;
    const float* ub = u + ((size_t)bb * 256 + h) * 8192;
    float* yb = out + ((size_t)bb * 256 + h) * 8192;

    const int mrow = (wv << 5) + (lane & 31);      // output row (pc / r)
    const int kh = (lane >> 5) << 3;               // k-offset within frag
    const int ncol = lane & 31;                    // output column (c)

    const _Float16* Wg = (const _Float16*)(ws + A2_BYTES) + (size_t)mrow * CM + kh;
    const _Float16* Ag = (const _Float16*)ws + ((size_t)h * CM + mrow) * 256 + kh;

    // ---- issue u loads (HBM) and W fragments (L2) up front ----
    float4 uv[8];
#pragma unroll
    for (int i = 0; i < 8; ++i) uv[i] = ((const float4*)ub)[i * 256 + tid];
    half8 wf[8];
#pragma unroll
    for (int s = 0; s < 8; ++s) wf[s] = *(const half8*)(Wg + (s << 4));

    // stage u -> fp16 swizzled tiles
#pragma unroll
    for (int i = 0; i < 8; ++i) {
        int e4 = i * 256 + tid;
        int c = e4 >> 5, j = (e4 << 2) & 127;
        half4v hv = { (_Float16)uv[i].x, (_Float16)uv[i].y,
                      (_Float16)uv[i].z, (_Float16)uv[i].w };
        *(half4v*)&u16[SWH(c, j)] = hv;
    }
    __syncthreads();

    // ---- GEMM1: S_in = W * u_chunks (A-fragments preloaded in wf) ----
    {
        floatx16 acc0 = {}; floatx16 acc1 = {};
#pragma unroll
        for (int s = 0; s < 8; ++s) {
            int k0 = (s << 4) + kh;
            half8 b0 = *(const half8*)&u16[SWH(ncol, k0)];
            half8 b1 = *(const half8*)&u16[SWH(ncol + 32, k0)];
            acc0 = __builtin_amdgcn_mfma_f32_32x32x16_f16(wf[s], b0, acc0, 0, 0, 0);
            acc1 = __builtin_amdgcn_mfma_f32_32x32x16_f16(wf[s], b1, acc1, 0, 0, 0);
        }
        const int pc0 = (wv << 5) + ((lane >> 5) << 2);
#pragma unroll
        for (int g = 0; g < 4; ++g) {
            half4v h0 = { (_Float16)acc0[4 * g + 0], (_Float16)acc0[4 * g + 1],
                          (_Float16)acc0[4 * g + 2], (_Float16)acc0[4 * g + 3] };
            *(half4v*)&S16[SWH(ncol, pc0 + 8 * g)] = h0;
            half4v h1 = { (_Float16)acc1[4 * g + 0], (_Float16)acc1[4 * g + 1],
                          (_Float16)acc1[4 * g + 2], (_Float16)acc1[4 * g + 3] };
            *(half4v*)&S16[SWH(ncol + 32, pc0 + 8 * g)] = h1;
        }
    }
    // issue GEMM2 G-part fragments now: L2 latency hides under the scan
    half8 gf[8];
#pragma unroll
    for (int s = 0; s < 8; ++s) gf[s] = *(const half8*)(Ag + (s << 4));
    __syncthreads();

    // ---- parallel chunk-state scan: wave wv owns chunks [16wv, 16wv+16) ----
    // Warm start via 8-tap truncated history (|A^128|^8 <= 3.4e-5), then serial.
    {
        const float* aM = (const float*)(ws + AM_OFF);
        const float amr = aM[lane], ami = aM[64 + lane];
        float prd[8], pid[8];                     // (A^128)^d
        prd[0] = 1.f; pid[0] = 0.f;
#pragma unroll
        for (int d = 1; d < 8; ++d) {
            prd[d] = prd[d - 1] * amr - pid[d - 1] * ami;
            pid[d] = prd[d - 1] * ami + pid[d - 1] * amr;
        }
        const int cbase = wv << 4;
        float sr = 0.f, si = 0.f;
#pragma unroll
        for (int d = 0; d < 8; ++d) {             // circular warm start
            int cc = (cbase - 1 - d) & 63;
            float xr = (float)S16[SWH(cc, lane)];
            float xi = (float)S16[SWH(cc, 64 + lane)];
            sr = fmaf(prd[d], xr, fmaf(-pid[d], xi, sr));
            si = fmaf(prd[d], xi, fmaf(pid[d], xr, si));
        }
        float er[16], ei[16];                     // ENTERING states (static-indexed)
        er[0] = sr; ei[0] = si;
#pragma unroll
        for (int i = 1; i < 16; ++i) {
            int cc = cbase + i - 1;
            float xr = (float)S16[SWH(cc, lane)];
            float xi = (float)S16[SWH(cc, 64 + lane)];
            float nr = fmaf(amr, sr, fmaf(-ami, si, xr));
            float ni = fmaf(amr, si, fmaf(ami, sr, xi));
            sr = nr; si = ni; er[i] = sr; ei[i] = si;
        }
        __syncthreads();   // everyone done READING S_in before overwrite
#pragma unroll
        for (int i = 0; i < 16; ++i) {
            int c = cbase + i;
            S16[SWH(c, lane)] = (_Float16)er[i];
            S16[SWH(c, 64 + lane)] = (_Float16)ei[i];
        }
    }
    // issue T'-part fragments: L2 latency hides under GEMM2 part 1
    half8 tf[8];
#pragma unroll
    for (int s = 0; s < 8; ++s) tf[s] = *(const half8*)(Ag + CM + (s << 4));
    __syncthreads();

    // ---- GEMM2: y = [G|T'] * [sB; u_chunk], then tanh + store ----
    {
        floatx16 acc0 = {}; floatx16 acc1 = {};
#pragma unroll
        for (int s = 0; s < 8; ++s) {          // k = 0..127: G * sB
            int k0 = (s << 4) + kh;
            half8 b0 = *(const half8*)&S16[SWH(ncol, k0)];
            half8 b1 = *(const half8*)&S16[SWH(ncol + 32, k0)];
            acc0 = __builtin_amdgcn_mfma_f32_32x32x16_f16(gf[s], b0, acc0, 0, 0, 0);
            acc1 = __builtin_amdgcn_mfma_f32_32x32x16_f16(gf[s], b1, acc1, 0, 0, 0);
        }
#pragma unroll
        for (int s = 0; s < 8; ++s) {          // k = 128..255: T' * u
            int k0 = (s << 4) + kh;
            half8 b0 = *(const half8*)&u16[SWH(ncol, k0)];
            half8 b1 = *(const half8*)&u16[SWH(ncol + 32, k0)];
            acc0 = __builtin_amdgcn_mfma_f32_32x32x16_f16(tf[s], b0, acc0, 0, 0, 0);
            acc1 = __builtin_amdgcn_mfma_f32_32x32x16_f16(tf[s], b1, acc1, 0, 0, 0);
        }
        const int r0 = (wv << 5) + ((lane >> 5) << 2);
#pragma unroll
        for (int g = 0; g < 4; ++g) {
            float4 o0;
            o0.x = fast_tanh(acc0[4 * g + 0]); o0.y = fast_tanh(acc0[4 * g + 1]);
            o0.z = fast_tanh(acc0[4 * g + 2]); o0.w = fast_tanh(acc0[4 * g + 3]);
            *(float4*)(yb + (size_t)ncol * CM + r0 + 8 * g) = o0;
            float4 o1;
            o1.x = fast_tanh(acc1[4 * g + 0]); o1.y = fast_tanh(acc1[4 * g + 1]);
            o1.z = fast_tanh(acc1[4 * g + 2]); o1.w = fast_tanh(acc1[4 * g + 3]);
            *(float4*)(yb + (size_t)(ncol + 32) * CM + r0 + 8 * g) = o1;
        }
    }
}

extern "C" void kernel_launch(void* const* d_in, const int* in_sizes, int n_in,
                              void* d_out, int out_size, void* d_ws, size_t ws_size,
                              hipStream_t stream) {
    const float* u     = (const float*)d_in[0];
    const float* A_re  = (const float*)d_in[1];
    const float* A_im  = (const float*)d_in[2];
    const float* BC_re = (const float*)d_in[3];
    const float* BC_im = (const float*)d_in[4];
    const float* Dv    = (const float*)d_in[5];
    float* out = (float*)d_out;
    char* ws = (char*)d_ws;

    hipLaunchKernelGGL(fftconv_prep, dim3(256), dim3(256), 0, stream,
                       A_re, A_im, BC_re, BC_im, Dv, ws);
    hipLaunchKernelGGL(fftconv_main, dim3(4096), dim3(256), 0, stream,
                       u, ws, out);
}